// Round 1
// baseline (1184.390 us; speedup 1.0000x reference)
//
#include <hip/hip_runtime.h>

#define T_TOK 16384
#define D_DIM 4096
#define E_EXP 64
#define NB (T_TOK / 64)   // 256 token blocks

// Main GEMM kernel: 1 wave per block, lane = token, acc[e] per lane.
// Expert loads are wave-uniform -> scalar (SMEM) loads; token loads are
// per-lane sequential float4 streams (L1 absorbs the 64-line scatter).
__global__ __launch_bounds__(64)
void moe_dot_kernel(const float* __restrict__ th, const float* __restrict__ eg,
                    float* __restrict__ partial, int ksplit, int bk) {
  const int tb   = blockIdx.x % NB;
  const int kc   = blockIdx.x / NB;
  const int lane = threadIdx.x;

  const float* __restrict__ trow = th + (size_t)(tb * 64 + lane) * D_DIM + (size_t)kc * bk;
  const float* __restrict__ ebase = eg + (size_t)kc * bk;

  float acc[E_EXP];
#pragma unroll
  for (int e = 0; e < E_EXP; ++e) acc[e] = 0.f;

  for (int k0 = 0; k0 < bk; k0 += 16) {
    const float4* tv4 = (const float4*)(trow + k0);
    float4 a = tv4[0];
    float4 b = tv4[1];
    float4 c = tv4[2];
    float4 d = tv4[3];
    float tv[16] = {a.x, a.y, a.z, a.w, b.x, b.y, b.z, b.w,
                    c.x, c.y, c.z, c.w, d.x, d.y, d.z, d.w};
#pragma unroll
    for (int e = 0; e < E_EXP; ++e) {
      const float* __restrict__ ep = ebase + (size_t)e * D_DIM + k0;  // wave-uniform addr
      float s = acc[e];
#pragma unroll
      for (int j = 0; j < 16; ++j) s = fmaf(ep[j], tv[j], s);
      acc[e] = s;
    }
  }

  // partial layout: [kc][tb][e][lane]  -> coalesced 256B stores per e
  float* __restrict__ pout = partial + (size_t)(kc * NB + tb) * E_EXP * 64;
#pragma unroll
  for (int e = 0; e < E_EXP; ++e) pout[e * 64 + lane] = acc[e];
}

// Reduce k-split partials, add router logits, streaming top-2 (+softmax of 2).
__global__ __launch_bounds__(64)
void moe_top2_kernel(const float* __restrict__ partial, const float* __restrict__ rl,
                     float* __restrict__ out, const float* __restrict__ alpha_p,
                     int ksplit) {
  const int tb   = blockIdx.x;
  const int lane = threadIdx.x;
  const int t    = tb * 64 + lane;
  const float alpha = alpha_p[0];

  float v1 = -3.4e38f, v2 = -3.4e38f;
  int i1 = 0, i2 = 0;
#pragma unroll
  for (int e = 0; e < E_EXP; ++e) {
    float dot = 0.f;
    for (int kc = 0; kc < ksplit; ++kc)
      dot += partial[((size_t)(kc * NB + tb) * E_EXP + e) * 64 + lane];
    float g = rl[(size_t)t * E_EXP + e] + alpha * dot;
    // strict > keeps earliest index on ties, matching lax.top_k tie-break
    if (g > v1) { v2 = v1; i2 = i1; v1 = g; i1 = e; }
    else if (g > v2) { v2 = g; i2 = e; }
  }
  // softmax over [v1, v2], v1 >= v2
  float ew  = __expf(v2 - v1);
  float inv = 1.f / (1.f + ew);
  float4 o  = make_float4((float)i1, inv, (float)i2, ew * inv);
  ((float4*)out)[t] = o;
}

extern "C" void kernel_launch(void* const* d_in, const int* in_sizes, int n_in,
                              void* d_out, int out_size, void* d_ws, size_t ws_size,
                              hipStream_t stream) {
  const float* th      = (const float*)d_in[0];  // [T, D]
  const float* rl      = (const float*)d_in[1];  // [T, E]
  const float* eg      = (const float*)d_in[2];  // [E, D]
  const float* alpha_p = (const float*)d_in[3];  // scalar
  float* out     = (float*)d_out;                // [T, 2, 2]
  float* partial = (float*)d_ws;

  // pick largest ksplit whose partial buffer fits in d_ws
  int ksplit = 8;
  while (ksplit > 1 &&
         (size_t)ksplit * NB * E_EXP * 64 * sizeof(float) > ws_size)
    ksplit >>= 1;
  int bk = D_DIM / ksplit;

  moe_dot_kernel<<<dim3(NB * ksplit), dim3(64), 0, stream>>>(th, eg, partial, ksplit, bk);
  moe_top2_kernel<<<dim3(NB), dim3(64), 0, stream>>>(partial, rl, out, alpha_p, ksplit);
}

// Round 2
// 444.029 us; speedup vs baseline: 2.6674x; 2.6674x over previous
//
#include <hip/hip_runtime.h>

typedef __attribute__((ext_vector_type(4))) float f32x4;
typedef __attribute__((ext_vector_type(8))) short short8;

#define T_TOK 16384
#define D_DIM 4096
#define E_EXP 64
#define BKC 128            // k elements per LDS staging chunk
#define GAP_THR 0.1f       // top-2 gap below which we recheck in exact fp32
#define LIST_CAP 8192

// Split fp32 -> bf16 hi (bit-truncate) + bf16 lo (truncate of exact residual).
// a = hi + lo + eps, |eps| <~ 2^-17 |a|; missing lo*lo term <~ 2^-16 per product.
__device__ __forceinline__ void cvt8(const float4& x, const float4& y,
                                     short8& hi, short8& lo) {
  float v[8] = {x.x, x.y, x.z, x.w, y.x, y.y, y.z, y.w};
#pragma unroll
  for (int j = 0; j < 8; ++j) {
    unsigned b = __float_as_uint(v[j]);
    hi[j] = (short)(b >> 16);
    float l = v[j] - __uint_as_float(b & 0xffff0000u);
    lo[j] = (short)(__float_as_uint(l) >> 16);
  }
}

// Pass 1: partial[kc][t][e] = dot(th[t], eg[e]) over this block's k-range,
// via 3-pass bf16 split MFMA. Block: 64 tokens x 64 experts, 4 waves.
__global__ __launch_bounds__(256, 4)
void moe_mfma_kernel(const float* __restrict__ th, const float* __restrict__ eg,
                     float* __restrict__ partial, int klen) {
  // B chunk in fragment order: [hi/lo][slot=ks*4+nt][lane][8 bf16] -> 32 KB
  __shared__ __align__(16) short lds_b[2 * 16 * 64 * 8];
  const int nb   = T_TOK / 64;
  const int tb   = blockIdx.x % nb;
  const int kc   = blockIdx.x / nb;
  const int tid  = threadIdx.x;
  const int wave = tid >> 6, lane = tid & 63;
  const int m    = lane & 15, quad = lane >> 4;

  const int k0  = kc * klen;
  const int tok = tb * 64 + wave * 16 + m;
  const float* aptr = th + (size_t)tok * D_DIM + k0 + quad * 8;

  f32x4 acc[4];
#pragma unroll
  for (int nt = 0; nt < 4; ++nt) acc[nt] = (f32x4){0.f, 0.f, 0.f, 0.f};

  const int nchunk = klen / BKC;
  for (int c = 0; c < nchunk; ++c) {
    __syncthreads();
    // Stage B chunk (64 experts x 128 k): wave stages slots [wave*4, wave*4+4).
    // Slot s holds exactly the 16B/lane fragment compute will read -> lane-linear,
    // conflict-free ds_write_b128 / ds_read_b128.
#pragma unroll
    for (int si = 0; si < 4; ++si) {
      int s  = wave * 4 + si;
      int ks = s >> 2, nt = s & 3;
      int n  = nt * 16 + m;
      const float* bp = eg + (size_t)n * D_DIM + k0 + c * BKC + ks * 32 + quad * 8;
      float4 x = *(const float4*)bp;
      float4 y = *(const float4*)(bp + 4);
      short8 hi, lo;
      cvt8(x, y, hi, lo);
      *(short8*)&lds_b[(s * 64 + lane) * 8] = hi;
      *(short8*)&lds_b[16 * 64 * 8 + (s * 64 + lane) * 8] = lo;
    }
    __syncthreads();
    const float* ap = aptr + c * BKC;
#pragma unroll
    for (int ks = 0; ks < BKC / 32; ++ks) {
      float4 x = *(const float4*)(ap + ks * 32);
      float4 y = *(const float4*)(ap + ks * 32 + 4);
      short8 ahi, alo;
      cvt8(x, y, ahi, alo);
#pragma unroll
      for (int nt = 0; nt < 4; ++nt) {
        short8 bhi = *(const short8*)&lds_b[((ks * 4 + nt) * 64 + lane) * 8];
        short8 blo = *(const short8*)&lds_b[16 * 64 * 8 + ((ks * 4 + nt) * 64 + lane) * 8];
        acc[nt] = __builtin_amdgcn_mfma_f32_16x16x32_bf16(ahi, bhi, acc[nt], 0, 0, 0);
        acc[nt] = __builtin_amdgcn_mfma_f32_16x16x32_bf16(ahi, blo, acc[nt], 0, 0, 0);
        acc[nt] = __builtin_amdgcn_mfma_f32_16x16x32_bf16(alo, bhi, acc[nt], 0, 0, 0);
      }
    }
  }
  // C/D layout: col(expert)=lane&15, row(token)=(lane>>4)*4+i
#pragma unroll
  for (int nt = 0; nt < 4; ++nt)
#pragma unroll
    for (int i = 0; i < 4; ++i) {
      int tokr = tb * 64 + wave * 16 + quad * 4 + i;
      partial[((size_t)kc * T_TOK + tokr) * E_EXP + nt * 16 + m] = acc[nt][i];
    }
}

__global__ void moe_init_kernel(int* cnt) {
  if (threadIdx.x == 0 && blockIdx.x == 0) *cnt = 0;
}

// Pass 2: reduce k-split partials, add router logits, wave-per-token top-2,
// softmax of 2, flag near-ties for exact recheck.
__global__ __launch_bounds__(256)
void moe_top2_kernel(const float* __restrict__ partial, const float* __restrict__ rl,
                     const float* __restrict__ alpha_p, float* __restrict__ out,
                     int* __restrict__ cnt, int* __restrict__ list, int nkc) {
  const int wave = threadIdx.x >> 6, lane = threadIdx.x & 63;
  const int t = blockIdx.x * 4 + wave;
  const float alpha = alpha_p[0];

  float dot = 0.f;
  for (int kc = 0; kc < nkc; ++kc)
    dot += partial[((size_t)kc * T_TOK + t) * E_EXP + lane];
  float g = rl[(size_t)t * E_EXP + lane] + alpha * dot;

  float v1 = g; int i1 = lane;
#pragma unroll
  for (int off = 32; off > 0; off >>= 1) {
    float vo = __shfl_down(v1, off, 64);
    int   io = __shfl_down(i1, off, 64);
    if (vo > v1 || (vo == v1 && io < i1)) { v1 = vo; i1 = io; }
  }
  v1 = __shfl(v1, 0, 64); i1 = __shfl(i1, 0, 64);

  float g2 = (lane == i1) ? -3.4e38f : g;
  float v2 = g2; int i2 = lane;
#pragma unroll
  for (int off = 32; off > 0; off >>= 1) {
    float vo = __shfl_down(v2, off, 64);
    int   io = __shfl_down(i2, off, 64);
    if (vo > v2 || (vo == v2 && io < i2)) { v2 = vo; i2 = io; }
  }

  if (lane == 0) {
    float ew  = __expf(v2 - v1);
    float inv = 1.f / (1.f + ew);
    ((float4*)out)[t] = make_float4((float)i1, inv, (float)i2, ew * inv);
    if (v1 - v2 < GAP_THR) {
      int idx = atomicAdd(cnt, 1);
      if (idx < LIST_CAP) list[idx] = t;
    }
  }
}

// Pass 3: exact fp32 recompute of flagged tokens (4 waves split k, lane=expert).
__global__ __launch_bounds__(256)
void moe_fix_kernel(const float* __restrict__ th, const float* __restrict__ eg,
                    const float* __restrict__ rl, const float* __restrict__ alpha_p,
                    float* __restrict__ out, const int* __restrict__ cnt,
                    const int* __restrict__ list) {
  __shared__ float lds_p[4][64];
  const int wave = threadIdx.x >> 6, lane = threadIdx.x & 63;
  const float alpha = alpha_p[0];
  int count = *cnt;
  if (count > LIST_CAP) count = LIST_CAP;

  for (int i = blockIdx.x; i < count; i += gridDim.x) {
    int t = list[i];
    const float* tr = th + (size_t)t * D_DIM + wave * 1024;
    const float* er = eg + (size_t)lane * D_DIM + wave * 1024;
    float d = 0.f;
    for (int k = 0; k < 1024; k += 4) {
      float4 a = *(const float4*)(tr + k);   // wave-uniform row
      float4 b = *(const float4*)(er + k);
      d = fmaf(a.x, b.x, d); d = fmaf(a.y, b.y, d);
      d = fmaf(a.z, b.z, d); d = fmaf(a.w, b.w, d);
    }
    lds_p[wave][lane] = d;
    __syncthreads();
    if (wave == 0) {
      float dot = lds_p[0][lane] + lds_p[1][lane] + lds_p[2][lane] + lds_p[3][lane];
      float g = rl[(size_t)t * E_EXP + lane] + alpha * dot;
      float v1 = g; int i1 = lane;
#pragma unroll
      for (int off = 32; off > 0; off >>= 1) {
        float vo = __shfl_down(v1, off, 64);
        int   io = __shfl_down(i1, off, 64);
        if (vo > v1 || (vo == v1 && io < i1)) { v1 = vo; i1 = io; }
      }
      v1 = __shfl(v1, 0, 64); i1 = __shfl(i1, 0, 64);
      float g2 = (lane == i1) ? -3.4e38f : g;
      float v2 = g2; int i2 = lane;
#pragma unroll
      for (int off = 32; off > 0; off >>= 1) {
        float vo = __shfl_down(v2, off, 64);
        int   io = __shfl_down(i2, off, 64);
        if (vo > v2 || (vo == v2 && io < i2)) { v2 = vo; i2 = io; }
      }
      if (lane == 0) {
        float ew  = __expf(v2 - v1);
        float inv = 1.f / (1.f + ew);
        ((float4*)out)[t] = make_float4((float)i1, inv, (float)i2, ew * inv);
      }
    }
    __syncthreads();
  }
}

extern "C" void kernel_launch(void* const* d_in, const int* in_sizes, int n_in,
                              void* d_out, int out_size, void* d_ws, size_t ws_size,
                              hipStream_t stream) {
  const float* th      = (const float*)d_in[0];  // [T, D]
  const float* rl      = (const float*)d_in[1];  // [T, E]
  const float* eg      = (const float*)d_in[2];  // [E, D]
  const float* alpha_p = (const float*)d_in[3];  // scalar
  float* out = (float*)d_out;                    // [T, 2, 2]

  int ksplit = 4;
  while (ksplit > 1 &&
         (size_t)ksplit * T_TOK * E_EXP * 4 + 256 + LIST_CAP * 4 > ws_size)
    ksplit >>= 1;
  int klen = D_DIM / ksplit;

  float* partial = (float*)d_ws;
  int* cnt  = (int*)((char*)d_ws + (size_t)ksplit * T_TOK * E_EXP * 4);
  int* list = cnt + 64;

  moe_init_kernel<<<1, 64, 0, stream>>>(cnt);
  moe_mfma_kernel<<<(T_TOK / 64) * ksplit, 256, 0, stream>>>(th, eg, partial, klen);
  moe_top2_kernel<<<T_TOK / 4, 256, 0, stream>>>(partial, rl, alpha_p, out, cnt, list, ksplit);
  moe_fix_kernel<<<256, 256, 0, stream>>>(th, eg, rl, alpha_p, out, cnt, list);
}